// Round 1
// baseline (6933.813 us; speedup 1.0000x reference)
//
#include <hip/hip_runtime.h>
#include <math.h>

#define T_STEPS 512
#define BATCH   16
#define DIM     1024
#define M_TOTAL (T_STEPS*BATCH)              // 8192
#define OUT_SEC ((size_t)M_TOTAL*DIM)        // 8388608 floats (output section)
#define G_BLOCKS 128

// ---------------------------------------------------------------------------
// wave-wide sum reduction (64 lanes)
__device__ __forceinline__ float wred64(float v){
  #pragma unroll
  for (int off = 32; off >= 1; off >>= 1) v += __shfl_xor(v, off, 64);
  return v;
}

// ---------------------------------------------------------------------------
// Kernel A: entmax-1.5 gate. One wave per row of z [8192 rows x 1024].
// Writes gate into d_out's OUTPUT section (recurrence kernel consumes it,
// then overwrites with the final output).
__global__ __launch_bounds__(256) void gate_kernel(const float* __restrict__ z,
                                                   float* __restrict__ gate_out){
  const int row  = blockIdx.x * 4 + (threadIdx.x >> 6);
  const int lane = threadIdx.x & 63;
  const float* zr = z + (size_t)row * DIM;

  float x[16];
  #pragma unroll
  for (int e = 0; e < 4; ++e){
    float4 v = *reinterpret_cast<const float4*>(zr + e*256 + lane*4);
    x[e*4+0]=v.x; x[e*4+1]=v.y; x[e*4+2]=v.z; x[e*4+3]=v.w;
  }

  // row max
  float m = x[0];
  #pragma unroll
  for (int i = 1; i < 16; ++i) m = fmaxf(m, x[i]);
  #pragma unroll
  for (int off = 32; off >= 1; off >>= 1) m = fmaxf(m, __shfl_xor(m, off, 64));

  // binary search for tau in [m-1, m]: f(tau)=sum relu(x-tau), f(lo)>=1>f(hi)
  float lo = m - 1.0f, hi = m;
  for (int it = 0; it < 30; ++it){
    float mid = 0.5f*(lo + hi);
    float f = 0.f;
    #pragma unroll
    for (int i = 0; i < 16; ++i) f += fmaxf(x[i] - mid, 0.f);
    f = wred64(f);
    if (f >= 1.0f) lo = mid; else hi = mid;
  }
  // exact threshold from the identified support (ties at tau* are harmless)
  float s = 0.f, kc = 0.f;
  #pragma unroll
  for (int i = 0; i < 16; ++i){ if (x[i] > lo){ s += x[i]; kc += 1.f; } }
  s = wred64(s); kc = wred64(kc);
  const float tau = (s - 1.0f) / kc;

  float p[16]; float ps = 0.f;
  #pragma unroll
  for (int i = 0; i < 16; ++i){ p[i] = sqrtf(fmaxf(x[i] - tau, 0.f)); ps += p[i]; }
  ps = wred64(ps);
  const float inv = 1.0f / (ps + 1e-10f);

  float* go = gate_out + (size_t)row * DIM;
  #pragma unroll
  for (int e = 0; e < 4; ++e){
    float4 v; v.x=p[e*4]*inv; v.y=p[e*4+1]*inv; v.z=p[e*4+2]*inv; v.w=p[e*4+3]*inv;
    *reinterpret_cast<float4*>(go + e*256 + lane*4) = v;
  }
}

// ---------------------------------------------------------------------------
// Kernel B: pre[t,b,:] = x[t,b,:] @ Wx^T + bias   (fp32 GEMM, M=8192,N=1024,K=1024)
// Written into d_out's H section at slot t+1 (the recurrence reads its own pre
// value then overwrites it with h[t+1]).
__global__ __launch_bounds__(256) void pre_gemm(const float* __restrict__ X,
                                                const float* __restrict__ Wx,
                                                const float* __restrict__ bias,
                                                float* __restrict__ out_h){
  __shared__ float a_s[64][17];
  __shared__ float w_s[64][17];
  const int tid = threadIdx.x;
  const int bm = blockIdx.x & 127, bn = blockIdx.x >> 7;
  const int m0 = bm*64, n0 = bn*64;
  const int lr = tid >> 2, lc = (tid & 3) * 4;
  const int tx = tid & 15, ty = tid >> 4;

  float acc[4][4] = {};

  for (int k0 = 0; k0 < DIM; k0 += 16){
    float4 av = *reinterpret_cast<const float4*>(X  + (size_t)(m0+lr)*DIM + k0 + lc);
    float4 wv = *reinterpret_cast<const float4*>(Wx + (size_t)(n0+lr)*DIM + k0 + lc);
    __syncthreads();
    a_s[lr][lc+0]=av.x; a_s[lr][lc+1]=av.y; a_s[lr][lc+2]=av.z; a_s[lr][lc+3]=av.w;
    w_s[lr][lc+0]=wv.x; w_s[lr][lc+1]=wv.y; w_s[lr][lc+2]=wv.z; w_s[lr][lc+3]=wv.w;
    __syncthreads();
    #pragma unroll
    for (int k = 0; k < 16; ++k){
      float af[4], wf[4];
      #pragma unroll
      for (int i = 0; i < 4; ++i) af[i] = a_s[ty*4+i][k];
      #pragma unroll
      for (int j = 0; j < 4; ++j) wf[j] = w_s[tx*4+j][k];
      #pragma unroll
      for (int i = 0; i < 4; ++i)
        #pragma unroll
        for (int j = 0; j < 4; ++j) acc[i][j] = fmaf(af[i], wf[j], acc[i][j]);
    }
  }

  const float4 bv = *reinterpret_cast<const float4*>(bias + n0 + tx*4);
  #pragma unroll
  for (int i = 0; i < 4; ++i){
    float4 v;
    v.x = acc[i][0]+bv.x; v.y = acc[i][1]+bv.y; v.z = acc[i][2]+bv.z; v.w = acc[i][3]+bv.w;
    // row m -> h slot m+BATCH  (pre[t] lives where h[t+1] will go)
    *reinterpret_cast<float4*>(out_h + (size_t)(m0+ty*4+i+BATCH)*DIM + n0 + tx*4) = v;
  }
}

// ---------------------------------------------------------------------------
// device-scope grid barrier (monotonic counter in ws, zeroed each launch)
__device__ __forceinline__ void grid_bar(unsigned* cnt, unsigned target){
  __syncthreads();
  if (threadIdx.x == 0){
    __threadfence();
    __hip_atomic_fetch_add(cnt, 1u, __ATOMIC_RELEASE, __HIP_MEMORY_SCOPE_AGENT);
    while (__hip_atomic_load(cnt, __ATOMIC_ACQUIRE, __HIP_MEMORY_SCOPE_AGENT) < target)
      __builtin_amdgcn_s_sleep(1);
  }
  __syncthreads();
}

// ---------------------------------------------------------------------------
// Kernel C: persistent recurrence. 128 blocks x 256 threads.
// Block owns 8 d_out rows; thread (dl, ks) owns W_h[d, {128j+4ks..+4}] j=0..7
// (32 weights register-resident). Per step: h_prev -> LDS, 512 FMAs/thread,
// shfl-reduce over 32 K-slice lanes, tanh, store h[t+1] & output[t].
__global__ __launch_bounds__(256) void rnn_kernel(const float* __restrict__ h0,
                                                  const float* __restrict__ Wh,
                                                  float* __restrict__ out,
                                                  unsigned* __restrict__ cnt){
  float* out_h = out + OUT_SEC;
  const int tid = threadIdx.x, bid = blockIdx.x;
  const int ks = tid & 31;        // K-slice 0..31
  const int dl = tid >> 5;        // 0..7
  const int d  = bid*8 + dl;

  __shared__ float hbuf[BATCH][DIM];   // 64 KB

  float4 w4[8];
  #pragma unroll
  for (int j = 0; j < 8; ++j)
    w4[j] = *reinterpret_cast<const float4*>(Wh + (size_t)d*DIM + j*128 + ks*4);

  // h[0] = h0  (each block copies its 1/128 slice)
  if (tid < 32)
    reinterpret_cast<float4*>(out_h)[bid*32 + tid] =
        reinterpret_cast<const float4*>(h0)[bid*32 + tid];

  unsigned bar = 1;
  grid_bar(cnt, (unsigned)G_BLOCKS * bar);

  for (int t = 0; t < T_STEPS; ++t){
    // stage h[t] into LDS (full 16x1024)
    const float4* src = reinterpret_cast<const float4*>(out_h + (size_t)t*BATCH*DIM);
    float4* dstl = reinterpret_cast<float4*>(&hbuf[0][0]);
    #pragma unroll
    for (int r = 0; r < 16; ++r) dstl[tid + 256*r] = src[tid + 256*r];

    // prefetch this thread's pre & gate (lane ks<16 produces batch b=ks)
    const size_t oidx = (size_t)(t+1)*BATCH*DIM + (size_t)ks*DIM + d;  // h slot t+1
    const size_t gidx = (size_t)t*BATCH*DIM + (size_t)ks*DIM + d;      // output slot t
    float pre_v = 0.f, gate_v = 0.f;
    if (ks < BATCH){ pre_v = out_h[oidx]; gate_v = out[gidx]; }

    __syncthreads();

    float acc[BATCH];
    #pragma unroll
    for (int b = 0; b < BATCH; ++b) acc[b] = 0.f;
    #pragma unroll
    for (int j = 0; j < 8; ++j){
      const int col = j*128 + ks*4;
      const float4 w = w4[j];
      #pragma unroll
      for (int b = 0; b < BATCH; ++b){
        const float4 h4 = *reinterpret_cast<const float4*>(&hbuf[b][col]);
        acc[b] = fmaf(w.x, h4.x, fmaf(w.y, h4.y, fmaf(w.z, h4.z, fmaf(w.w, h4.w, acc[b]))));
      }
    }

    // reduce over the 32 K-slice lanes (stays within each 32-lane half-wave);
    // static select avoids runtime-indexed array -> scratch (rule #20)
    float myv = 0.f;
    #pragma unroll
    for (int b = 0; b < BATCH; ++b){
      float v = acc[b];
      v += __shfl_xor(v, 1, 64);
      v += __shfl_xor(v, 2, 64);
      v += __shfl_xor(v, 4, 64);
      v += __shfl_xor(v, 8, 64);
      v += __shfl_xor(v, 16, 64);
      if (ks == b) myv = v;
    }

    if (ks < BATCH){
      const float hn = tanhf(pre_v + myv);
      out_h[oidx] = hn;          // h[t+1]  (overwrites pre slot)
      out[gidx]  = hn * gate_v;  // output[t] (overwrites gate slot)
    }

    if (t != T_STEPS - 1){
      ++bar;
      grid_bar(cnt, (unsigned)G_BLOCKS * bar);
    }
  }
}

// ---------------------------------------------------------------------------
extern "C" void kernel_launch(void* const* d_in, const int* in_sizes, int n_in,
                              void* d_out, int out_size, void* d_ws, size_t ws_size,
                              hipStream_t stream){
  (void)in_sizes; (void)n_in; (void)out_size; (void)ws_size;
  const float* x    = (const float*)d_in[0];
  const float* z    = (const float*)d_in[1];
  const float* h0   = (const float*)d_in[2];
  const float* Wx   = (const float*)d_in[3];
  const float* Wh   = (const float*)d_in[4];
  const float* bias = (const float*)d_in[5];
  float* out   = (float*)d_out;
  float* out_h = out + OUT_SEC;
  unsigned* cnt = (unsigned*)d_ws;

  hipMemsetAsync(d_ws, 0, 256, stream);                       // reset barrier counter
  gate_kernel<<<2048, 256, 0, stream>>>(z, out);              // gate -> output section
  pre_gemm   <<<2048, 256, 0, stream>>>(x, Wx, bias, out_h);  // pre  -> h section (t+1)
  rnn_kernel <<<G_BLOCKS, 256, 0, stream>>>(h0, Wh, out, cnt);
}